// Round 1
// baseline (143.534 us; speedup 1.0000x reference)
//
#include <hip/hip_runtime.h>
#include <hip/hip_bf16.h>

// Problem constants: B=32, S=20 -> 640 graphs; N=128 nodes, F=64, HEADS=4, D=64.
#define ADJ_TH 0.05f

typedef __bf16 bf16x8 __attribute__((ext_vector_type(8)));
typedef __bf16 bf16x4 __attribute__((ext_vector_type(4)));
typedef float  f32x4  __attribute__((ext_vector_type(4)));

// ---- tiny pre-kernel: W [64][256] f32 -> Wt [256][64] bf16 (in d_ws) ----
__global__ void wt_convert_kernel(const float* __restrict__ W, __bf16* __restrict__ Wt) {
    int id = blockIdx.x * 256 + threadIdx.x;   // 0..16383
    int o = id >> 6, k = id & 63;
    Wt[o * 64 + k] = (__bf16)W[k * 256 + o];
}

// Swizzled element index into ht_t [256 rows (o)][128 cols (node i)] bf16.
// Rows are 256B (16 chunks of 16B); chunk index XORed with (o&15) so that
// GEMM2 B-fragment reads (16 lanes reading 16 consecutive o at same j-range)
// are bank-conflict-free.
__device__ __forceinline__ int sw_idx(int o, int i) {
    return o * 128 + ((((i >> 3) ^ o) & 15) << 3) + (i & 7);
}

__global__ __launch_bounds__(256, 2)
void gat_main_kernel(const float* __restrict__ hg, const float* __restrict__ adj,
                     const float* __restrict__ ag, const __bf16* __restrict__ Wt,
                     float* __restrict__ out)
{
    const int bs  = blockIdx.x;        // 0..639
    const int tid = threadIdx.x;       // 256 threads = 4 waves
    const int w   = tid >> 6;          // wave id 0..3
    const int l   = tid & 63;
    const int l15 = l & 15;
    const int l4  = l >> 4;

    __shared__ __bf16   ht_t[256 * 128];   // 64 KB, transposed+swizzled ht (bf16)
    __shared__ float    srctgt[1024];      // src [0..511] = [h][i], tgt [512..1023]
    __shared__ float    a_sh[512];         // a, flat (h*128 + d); src d<64, tgt d>=64
    __shared__ unsigned mask_sh[512];      // [i][4] bitmask words, bit j&31 of word j>>5

    const float* hb = hg  + (size_t)bs * 128 * 64;
    const float* ab = adj + (size_t)bs * 128 * 128;

    // ---------- phase 0a: a -> LDS ----------
    a_sh[tid]       = ag[tid];
    a_sh[tid + 256] = ag[tid + 256];

    // ---------- phase 0b: adjacency mask bits ----------
    #pragma unroll
    for (int rp = 0; rp < 2; ++rp) {
        int widx = tid + rp * 256;          // 0..511
        int i = widx >> 2, wq = widx & 3;
        const float4* ap = reinterpret_cast<const float4*>(ab + i * 128 + wq * 32);
        unsigned bits = 0u;
        #pragma unroll
        for (int v = 0; v < 8; ++v) {
            float4 f = ap[v];
            bits |= (f.x < ADJ_TH ? 1u : 0u) << (4 * v + 0);
            bits |= (f.y < ADJ_TH ? 1u : 0u) << (4 * v + 1);
            bits |= (f.z < ADJ_TH ? 1u : 0u) << (4 * v + 2);
            bits |= (f.w < ADJ_TH ? 1u : 0u) << (4 * v + 3);
        }
        mask_sh[i * 4 + wq] = bits;
    }

    // ---------- phase 0c: GEMM1  ht = h @ W  -> ht_t (bf16, transposed, swizzled) ----------
    {
        // A fragments: h rows for this wave's two 16-row tiles, K=64 (2 k-slices)
        bf16x8 af[2][2];
        #pragma unroll
        for (int m2 = 0; m2 < 2; ++m2) {
            int row = 16 * (2 * w + m2) + l15;
            #pragma unroll
            for (int ks = 0; ks < 2; ++ks) {
                const float4* p4 = reinterpret_cast<const float4*>(hb + row * 64 + 8 * l4 + 32 * ks);
                float4 lo = p4[0], hi = p4[1];
                bf16x8 v;
                v[0] = (__bf16)lo.x; v[1] = (__bf16)lo.y; v[2] = (__bf16)lo.z; v[3] = (__bf16)lo.w;
                v[4] = (__bf16)hi.x; v[5] = (__bf16)hi.y; v[6] = (__bf16)hi.z; v[7] = (__bf16)hi.w;
                af[m2][ks] = v;
            }
        }
        #pragma unroll
        for (int nt = 0; nt < 16; ++nt) {
            int o = 16 * nt + l15;
            bf16x8 bf0 = *reinterpret_cast<const bf16x8*>(Wt + o * 64 + 8 * l4);
            bf16x8 bf1 = *reinterpret_cast<const bf16x8*>(Wt + o * 64 + 8 * l4 + 32);
            #pragma unroll
            for (int m2 = 0; m2 < 2; ++m2) {
                f32x4 acc = {0.f, 0.f, 0.f, 0.f};
                acc = __builtin_amdgcn_mfma_f32_16x16x32_bf16(af[m2][0], bf0, acc, 0, 0, 0);
                acc = __builtin_amdgcn_mfma_f32_16x16x32_bf16(af[m2][1], bf1, acc, 0, 0, 0);
                // C/D: col = l&15 (channel o), rows = 16*mt + 4*l4 + r  -> ht_t[o][i0..i0+3]
                int i0 = 16 * (2 * w + m2) + 4 * l4;
                bf16x4 st;
                st[0] = (__bf16)acc[0]; st[1] = (__bf16)acc[1];
                st[2] = (__bf16)acc[2]; st[3] = (__bf16)acc[3];
                *reinterpret_cast<bf16x4*>(&ht_t[sw_idx(o, i0)]) = st;
            }
        }
    }
    __syncthreads();

    // ---------- phase 1: src/tgt projections (per head, per node) ----------
    #pragma unroll
    for (int rp = 0; rp < 2; ++rp) {
        int p = tid + rp * 256;            // 0..511 -> (head, node)
        int hh = p >> 7, i = p & 127;
        float s = 0.f, g = 0.f;
        #pragma unroll
        for (int d = 0; d < 64; ++d) {
            float v = (float)ht_t[sw_idx(hh * 64 + d, i)];
            s += v * a_sh[hh * 128 + d];
            g += v * a_sh[hh * 128 + 64 + d];
        }
        srctgt[hh * 128 + i]       = s;
        srctgt[512 + hh * 128 + i] = g;
    }
    __syncthreads();

    // ---------- phase 2: per-head masked softmax + GEMM2, head-mean in registers ----------
    f32x4 acc2[2][4];
    #pragma unroll
    for (int m2 = 0; m2 < 2; ++m2)
        #pragma unroll
        for (int nt = 0; nt < 4; ++nt) {
            f32x4 z = {0.f, 0.f, 0.f, 0.f};
            acc2[m2][nt] = z;
        }

    #pragma unroll 1
    for (int hd = 0; hd < 4; ++hd) {
        // B fragments: this head's entire ht_h (128 j x 64 d) -> 16 frags (64 VGPR)
        bf16x8 bfr[4][4];
        #pragma unroll
        for (int nt = 0; nt < 4; ++nt)
            #pragma unroll
            for (int ks = 0; ks < 4; ++ks)
                bfr[nt][ks] = *reinterpret_cast<const bf16x8*>(
                    &ht_t[sw_idx(64 * hd + 16 * nt + l15, 8 * l4 + 32 * ks)]);

        // tgt values for this lane's j-set
        float tg[4][8];
        #pragma unroll
        for (int ks = 0; ks < 4; ++ks) {
            const float4* tp = reinterpret_cast<const float4*>(&srctgt[512 + hd * 128 + 8 * l4 + 32 * ks]);
            float4 t0 = tp[0], t1 = tp[1];
            tg[ks][0] = t0.x; tg[ks][1] = t0.y; tg[ks][2] = t0.z; tg[ks][3] = t0.w;
            tg[ks][4] = t1.x; tg[ks][5] = t1.y; tg[ks][6] = t1.z; tg[ks][7] = t1.w;
        }

        #pragma unroll
        for (int m2 = 0; m2 < 2; ++m2) {
            int irow = 16 * (2 * w + m2) + l15;
            float si = srctgt[hd * 128 + irow];
            unsigned mw[4];
            #pragma unroll
            for (int ks = 0; ks < 4; ++ks) mw[ks] = mask_sh[irow * 4 + ks];

            float pf[4][8];
            float dloc = 0.f;
            #pragma unroll
            for (int ks = 0; ks < 4; ++ks)
                #pragma unroll
                for (int e = 0; e < 8; ++e) {
                    float x  = si + tg[ks][e];
                    float sg = __builtin_amdgcn_rcpf(1.0f + __expf(-x));   // sigmoid
                    float pe = __expf(sg);                                  // softmax numerator
                    float p  = ((mw[ks] >> (8 * l4 + e)) & 1u) ? 0.f : pe;
                    pf[ks][e] = p;
                    dloc += p;
                }
            // row sum across the 4 lane-groups owning this row
            dloc += __shfl_xor(dloc, 16);
            dloc += __shfl_xor(dloc, 32);
            float scale = 0.25f * __builtin_amdgcn_rcpf(fmaxf(dloc, 1e-20f));  // 1/den * head-mean

            bf16x8 pa[4];
            #pragma unroll
            for (int ks = 0; ks < 4; ++ks) {
                bf16x8 v;
                #pragma unroll
                for (int e = 0; e < 8; ++e) v[e] = (__bf16)(pf[ks][e] * scale);
                pa[ks] = v;
            }
            #pragma unroll
            for (int nt = 0; nt < 4; ++nt) {
                f32x4 acc = acc2[m2][nt];
                #pragma unroll
                for (int ks = 0; ks < 4; ++ks)
                    acc = __builtin_amdgcn_mfma_f32_16x16x32_bf16(pa[ks], bfr[nt][ks], acc, 0, 0, 0);
                acc2[m2][nt] = acc;
            }
        }
    }

    // ---------- epilogue: write out [128][64] f32 ----------
    float* ob = out + (size_t)bs * 128 * 64;
    #pragma unroll
    for (int m2 = 0; m2 < 2; ++m2)
        #pragma unroll
        for (int nt = 0; nt < 4; ++nt)
            #pragma unroll
            for (int r = 0; r < 4; ++r)
                ob[(32 * w + 16 * m2 + 4 * l4 + r) * 64 + 16 * nt + l15] = acc2[m2][nt][r];
}

extern "C" void kernel_launch(void* const* d_in, const int* in_sizes, int n_in,
                              void* d_out, int out_size, void* d_ws, size_t ws_size,
                              hipStream_t stream) {
    const float* h   = (const float*)d_in[0];
    const float* adj = (const float*)d_in[1];
    const float* W   = (const float*)d_in[2];
    const float* a   = (const float*)d_in[3];
    float* out = (float*)d_out;
    __bf16* Wt = (__bf16*)d_ws;   // 16384 bf16 = 32 KB scratch

    wt_convert_kernel<<<64, 256, 0, stream>>>(W, Wt);
    gat_main_kernel<<<640, 256, 0, stream>>>(h, adj, a, Wt, out);
}